// Round 1
// 2823.961 us; speedup vs baseline: 1.1712x; 1.1712x over previous
//
#include <hip/hip_runtime.h>
#include <cstdint>

typedef __bf16 bf16;
typedef __bf16 bf16x8 __attribute__((ext_vector_type(8)));
typedef float f32x4 __attribute__((ext_vector_type(4)));

#define B_  8
#define T_  2048
#define E_  2048
#define FF_ 8192
#define M_  (B_ * T_)   // 16384 rows total

// ---------------------------------------------------------------------------
__device__ __forceinline__ void gload_lds16(const void* g, void* l) {
    __builtin_amdgcn_global_load_lds(
        (const __attribute__((address_space(1))) uint32_t*)(uintptr_t)g,
        (__attribute__((address_space(3))) uint32_t*)(uintptr_t)l,
        16, 0, 0);
}

// ---------------------------------------------------------------------------
__global__ __launch_bounds__(256) void cvt_kernel(const float* __restrict__ src,
                                                  bf16* __restrict__ dst, int n8) {
    int i = blockIdx.x * 256 + threadIdx.x;
    if (i >= n8) return;
    const float4* s = (const float4*)src + (size_t)i * 2;
    float4 a = s[0], b = s[1];
    bf16x8 o;
    o[0] = (bf16)a.x; o[1] = (bf16)a.y; o[2] = (bf16)a.z; o[3] = (bf16)a.w;
    o[4] = (bf16)b.x; o[5] = (bf16)b.y; o[6] = (bf16)b.z; o[7] = (bf16)b.w;
    *(bf16x8*)&dst[(size_t)i * 8] = o;
}

// ---------------------------------------------------------------------------
__global__ __launch_bounds__(256) void ln_kernel(const float* __restrict__ x,
                                                 const float* __restrict__ gamma,
                                                 const float* __restrict__ beta,
                                                 bf16* __restrict__ out) {
    int row = blockIdx.x;
    int tid = threadIdx.x;
    const float* xr = x + (size_t)row * E_;
    float4 v0 = *(const float4*)&xr[tid * 8];
    float4 v1 = *(const float4*)&xr[tid * 8 + 4];
    float xs[8] = {v0.x, v0.y, v0.z, v0.w, v1.x, v1.y, v1.z, v1.w};
    float s = 0.f, s2 = 0.f;
#pragma unroll
    for (int j = 0; j < 8; j++) { s += xs[j]; s2 += xs[j] * xs[j]; }
#pragma unroll
    for (int o = 32; o > 0; o >>= 1) { s += __shfl_xor(s, o); s2 += __shfl_xor(s2, o); }
    __shared__ float red[8];
    int wave = tid >> 6, lane = tid & 63;
    if (lane == 0) { red[wave] = s; red[4 + wave] = s2; }
    __syncthreads();
    s  = red[0] + red[1] + red[2] + red[3];
    s2 = red[4] + red[5] + red[6] + red[7];
    float mean = s * (1.0f / E_);
    float var  = s2 * (1.0f / E_) - mean * mean;
    float rstd = rsqrtf(var + 1e-5f);
    float4 g0 = *(const float4*)&gamma[tid * 8];
    float4 g1 = *(const float4*)&gamma[tid * 8 + 4];
    float4 b0 = *(const float4*)&beta[tid * 8];
    float4 b1 = *(const float4*)&beta[tid * 8 + 4];
    float gs[8] = {g0.x, g0.y, g0.z, g0.w, g1.x, g1.y, g1.z, g1.w};
    float bs[8] = {b0.x, b0.y, b0.z, b0.w, b1.x, b1.y, b1.z, b1.w};
    bf16x8 o;
#pragma unroll
    for (int j = 0; j < 8; j++)
        o[j] = (bf16)((xs[j] - mean) * rstd * gs[j] + bs[j]);
    *(bf16x8*)&out[(size_t)row * E_ + tid * 8] = o;
}

// ---------------------------------------------------------------------------
__global__ __launch_bounds__(256) void softmax_kernel(bf16* __restrict__ S) {
    int row = blockIdx.x;
    int b = row >> 11;
    int t = row & (T_ - 1);
    bf16* p = S + (size_t)b * T_ * T_ + (size_t)t * T_;
    int L = t + 1;
    int Lpad = ((t >> 7) + 1) << 7;
    int tid = threadIdx.x;
    int wave = tid >> 6, lane = tid & 63;
    float v[8];
    float m = -3.0e38f;
#pragma unroll
    for (int j = 0; j < 8; j++) {
        int s = tid + j * 256;
        v[j] = (s < L) ? (float)p[s] : -3.0e38f;
        m = fmaxf(m, v[j]);
    }
#pragma unroll
    for (int o = 32; o > 0; o >>= 1) m = fmaxf(m, __shfl_xor(m, o));
    __shared__ float red[8];
    if (lane == 0) red[wave] = m;
    __syncthreads();
    m = fmaxf(fmaxf(red[0], red[1]), fmaxf(red[2], red[3]));
    float sum = 0.f;
#pragma unroll
    for (int j = 0; j < 8; j++) {
        int s = tid + j * 256;
        float e = (s < L) ? __expf(v[j] - m) : 0.f;
        v[j] = e;
        sum += e;
    }
#pragma unroll
    for (int o = 32; o > 0; o >>= 1) sum += __shfl_xor(sum, o);
    if (lane == 0) red[4 + wave] = sum;
    __syncthreads();
    sum = red[4] + red[5] + red[6] + red[7];
    float inv = 1.0f / sum;
#pragma unroll
    for (int j = 0; j < 8; j++) {
        int s = tid + j * 256;
        if (s < Lpad) p[s] = (bf16)(v[j] * inv);
    }
}

// ---------------------------------------------------------------------------
// bt-GEMM (128x128 tile, legacy structure) — still used for:
// MODE: 1 = QK^T: bf16*scale, causal tile skip (z=batch)
//       3 = PV: z=batch, K truncated at diagonal, bf16 out
template <int MODE>
__global__ __launch_bounds__(256) void gemm_bt(
    const bf16* __restrict__ A, const bf16* __restrict__ B,
    int K, int lda, int ldb, int ldc,
    long sA, long sB, long sC,
    void* __restrict__ Cv,
    const float* __restrict__ bias,
    const float* __restrict__ resid,
    float scale, int flags) {
    constexpr int BM = 128, BN = 128, BK = 32;
    int bz = blockIdx.z;
    int tm, tn;
    if (MODE == 1 || MODE == 3) {
        tm = blockIdx.x; tn = blockIdx.y;
    } else {
        int p = blockIdx.x + gridDim.x * blockIdx.y;
        int per = 32 * gridDim.y;
        int grp = p / per;
        int rem = p - grp * per;
        tm = grp * 32 + (rem & 31);
        tn = rem >> 5;
    }
    if (MODE == 1 && tn > tm) return;

    __shared__ bf16 As[BM * BK];
    __shared__ bf16 Bs[BN * BK];

    const int tid = threadIdx.x;
    const int wave = tid >> 6, lane = tid & 63;
    const int l15 = lane & 15, quad = lane >> 4;
    const int wm = wave >> 1, wn = wave & 1;

    const bf16* Ab = A + sA * bz + (size_t)tm * BM * lda;
    const bf16* Bb = B + sB * bz + (size_t)tn * BN * ldb;

    int Keff = K;
    if (MODE == 3) Keff = min(K, (tm + 1) * BM);

    f32x4 acc[4][4];
#pragma unroll
    for (int i = 0; i < 4; i++)
#pragma unroll
        for (int j = 0; j < 4; j++) { acc[i][j][0] = 0.f; acc[i][j][1] = 0.f; acc[i][j][2] = 0.f; acc[i][j][3] = 0.f; }

    const int srow = wave * 16 + (lane >> 2);
    const int scol = (lane & 3) * 8;

    for (int k0 = 0; k0 < Keff; k0 += BK) {
#pragma unroll
        for (int u = 0; u < 2; u++) {
            gload_lds16(Ab + (size_t)(u * 64 + srow) * lda + k0 + scol,
                        &As[(u * 64 + wave * 16) * BK]);
            gload_lds16(Bb + (size_t)(u * 64 + srow) * ldb + k0 + scol,
                        &Bs[(u * 64 + wave * 16) * BK]);
        }
        __syncthreads();
        bf16x8 af[4], bF[4];
#pragma unroll
        for (int mi = 0; mi < 4; mi++)
            af[mi] = *(const bf16x8*)&As[(wm * 64 + mi * 16 + l15) * BK + quad * 8];
#pragma unroll
        for (int ni = 0; ni < 4; ni++)
            bF[ni] = *(const bf16x8*)&Bs[(wn * 64 + ni * 16 + l15) * BK + quad * 8];
#pragma unroll
        for (int mi = 0; mi < 4; mi++)
#pragma unroll
            for (int ni = 0; ni < 4; ni++)
                acc[mi][ni] = __builtin_amdgcn_mfma_f32_16x16x32_bf16(af[mi], bF[ni], acc[mi][ni], 0, 0, 0);
        __syncthreads();
    }

    const int rb = tm * BM + wm * 64;
    const int cb = tn * BN + wn * 64;

    if (MODE == 1 || MODE == 3) {
        bf16* C = (bf16*)Cv + sC * bz;
#pragma unroll
        for (int mi = 0; mi < 4; mi++)
#pragma unroll
            for (int r = 0; r < 4; r++) {
                int row = rb + mi * 16 + quad * 4 + r;
#pragma unroll
                for (int ni = 0; ni < 4; ni++) {
                    int col = cb + ni * 16 + l15;
                    float v = acc[mi][ni][r];
                    if (MODE == 1) v *= scale;
                    C[(size_t)row * ldc + col] = (bf16)v;
                }
            }
    }
}

// ---------------------------------------------------------------------------
// 256x256-tile, BK=64, 8-wave, 4-phase-per-K-tile GEMM (T2+T3+T4+T5 stack).
// C[M,N] = A[M,K] * B[N,K]^T
// MODE: 4 = fp32 out = acc + bias[col] + resid[idx]
//       5 = bf16 out = relu(acc + bias[col])
//       6 = fp32 out: C[idx] += acc + (flags ? bias[col] : 0)
//
// LDS: lds[buf][A/B][half][khalf][128*32 bf16]  (8 KiB eighth-regions, 128 KiB total)
// Swizzle (both staging SOURCE and ds_read addr): b ^= (b>>4)&0x30  (st_16x32)
// Staging: 2 x global_load_lds_dwordx4 per phase; counted vmcnt(8) at P2/P4 only.
template <int MODE>
__global__ __launch_bounds__(512, 2) void gemm256(
    const bf16* __restrict__ A, const bf16* __restrict__ B,
    int K, int lda, int ldb, int ldc,
    void* __restrict__ Cv,
    const float* __restrict__ bias,
    const float* __restrict__ resid,
    int flags) {
    __shared__ bf16 lds[2][2][2][2][4096];

    const int tid  = threadIdx.x;
    const int lane = tid & 63;
    const int l15  = lane & 15, quad = lane >> 4;
    const int wave = tid >> 6;
    const int wm = wave >> 2;         // 0..1  (M half)
    const int wn = wave & 3;          // 0..3  (N quarter)
    const int bh = wn >> 1, bq = wn & 1;

    // XCD-bijective block swizzle (nwg % 8 == 0 for all call sites)
    int p   = blockIdx.x + gridDim.x * blockIdx.y;
    int nwg = gridDim.x * gridDim.y;
    int cpx = nwg >> 3;
    int w   = (p & 7) * cpx + (p >> 3);
    int tn_ = w % gridDim.y;
    int tm_ = w / gridDim.y;

    const int NT = K >> 6;            // K-tiles of 64 (always even here)

    // staging geometry: dest byte d = tid*16 (linear), source = swz(d)
    int d    = tid * 16;
    int lsw  = d ^ ((d >> 4) & 0x30);
    int srow = lsw >> 6;              // 0..127
    int ske  = (lsw & 63) >> 1;       // 0,8,16,24
    int wq   = wave * 1024;           // wave-uniform LDS byte offset

    const bf16* As0 = A + (size_t)(tm_ * 256 + srow) * lda + ske;
    const bf16* As1 = As0 + (size_t)128 * lda;
    const bf16* Bs0 = B + (size_t)(tn_ * 256 + srow) * ldb + ske;
    const bf16* Bs1 = Bs0 + (size_t)128 * ldb;

    // ds_read per-thread offset (swizzle folds to a per-thread constant)
    const int roff = (l15 * 64 + quad * 16) ^ ((l15 & 12) << 2);

    f32x4 acc[8][4];
#pragma unroll
    for (int i = 0; i < 8; i++)
#pragma unroll
        for (int j = 0; j < 4; j++) {
            acc[i][j][0] = 0.f; acc[i][j][1] = 0.f; acc[i][j][2] = 0.f; acc[i][j][3] = 0.f;
        }

    bf16x8 bfr[4];

#define STG(P0, P1, CB, R0, R1)                                                        \
    do {                                                                               \
        gload_lds16((P0) + (CB), (char*)(R0) + wq);                                    \
        gload_lds16((P1) + (CB), (char*)(R1) + wq);                                    \
    } while (0)

    // prologue: tile0 k0 (A,B), tile0 k1 (A,B), tile1 k0 (A,B) = 12 loads
    STG(As0, As1, 0,  &lds[0][0][0][0][0], &lds[0][0][1][0][0]);
    STG(Bs0, Bs1, 0,  &lds[0][1][0][0][0], &lds[0][1][1][0][0]);
    STG(As0, As1, 32, &lds[0][0][0][1][0], &lds[0][0][1][1][0]);
    STG(Bs0, Bs1, 32, &lds[0][1][0][1][0], &lds[0][1][1][1][0]);
    STG(As0, As1, 64, &lds[1][0][0][0][0], &lds[1][0][1][0][0]);
    STG(Bs0, Bs1, 64, &lds[1][1][0][0][0], &lds[1][1][1][0][0]);
    asm volatile("s_waitcnt vmcnt(8)" ::: "memory");   // retire tile0 k0
    __builtin_amdgcn_s_barrier();

#define PH(Q, KK, H, DOB, SP0, SP1, SCB, SR0, SR1, DOVM)                               \
    do {                                                                               \
        const char* ar_ = (const char*)&lds[(Q)][0][wm][(KK)][0] + (H) * 4096 + roff;  \
        bf16x8 a_[4];                                                                  \
        _Pragma("unroll")                                                              \
        for (int mi = 0; mi < 4; mi++)                                                 \
            a_[mi] = *(const bf16x8*)(ar_ + mi * 1024);                                \
        if (DOB) {                                                                     \
            const char* br_ = (const char*)&lds[(Q)][1][bh][(KK)][0] + bq * 4096 + roff; \
            _Pragma("unroll")                                                          \
            for (int ni = 0; ni < 4; ni++)                                             \
                bfr[ni] = *(const bf16x8*)(br_ + ni * 1024);                           \
        }                                                                              \
        STG(SP0, SP1, SCB, SR0, SR1);                                                  \
        __builtin_amdgcn_s_barrier();                                                  \
        __builtin_amdgcn_s_setprio(1);                                                 \
        _Pragma("unroll")                                                              \
        for (int mi = 0; mi < 4; mi++)                                                 \
            _Pragma("unroll")                                                          \
            for (int ni = 0; ni < 4; ni++)                                             \
                acc[(H) * 4 + mi][ni] = __builtin_amdgcn_mfma_f32_16x16x32_bf16(       \
                    a_[mi], bfr[ni], acc[(H) * 4 + mi][ni], 0, 0, 0);                  \
        __builtin_amdgcn_s_setprio(0);                                                 \
        if (DOVM) asm volatile("s_waitcnt vmcnt(8)" ::: "memory");                     \
        __builtin_amdgcn_s_barrier();                                                  \
    } while (0)

    // tile u in buf Q; stage u+1's k1 (P1:A, P2:B -> buf Q^1) and
    // u+2's k0 (P3:A, P4:B -> buf Q). Counted vmcnt(8) at P2/P4.
#define TILE(Q, WS1, WS2)                                                                              \
    do {                                                                                               \
        PH(Q, 0, 0, 1, As0, As1, (WS1) * 64 + 32, &lds[(Q) ^ 1][0][0][1][0], &lds[(Q) ^ 1][0][1][1][0], 0); \
        PH(Q, 0, 1, 0, Bs0, Bs1, (WS1) * 64 + 32, &lds[(Q) ^ 1][1][0][1][0], &lds[(Q) ^ 1][1][1][1][0], 1); \
        PH(Q, 1, 0, 1, As0, As1, (WS2) * 64, &lds[(Q)][0][0][0][0], &lds[(Q)][0][1][0][0], 0);         \
        PH(Q, 1, 1, 0, Bs0, Bs1, (WS2) * 64, &lds[(Q)][1][0][0][0], &lds[(Q)][1][1][0][0], 1);         \
    } while (0)

    for (int t = 0; t < NT; t += 2) {
        int wa = t + 1;                               // tile t stages (t+1).k1
        int wb = (t + 2 < NT) ? t + 2 : NT - 1;       // tile t stages (t+2).k0 ; tile t+1 stages (t+2).k1
        int wd = (t + 3 < NT) ? t + 3 : NT - 1;       // tile t+1 stages (t+3).k0
        TILE(0, wa, wb);
        TILE(1, wb, wd);
    }
    asm volatile("s_waitcnt vmcnt(0)" ::: "memory");

#undef TILE
#undef PH
#undef STG

    // epilogue
    const int rb0 = tm_ * 256 + wm * 128;
    const int cb0 = tn_ * 256 + wn * 64;
    if (MODE == 4) {
        float* C = (float*)Cv;
#pragma unroll
        for (int mf = 0; mf < 8; mf++)
#pragma unroll
            for (int r = 0; r < 4; r++) {
                int row = rb0 + mf * 16 + quad * 4 + r;
#pragma unroll
                for (int nf = 0; nf < 4; nf++) {
                    int col = cb0 + nf * 16 + l15;
                    size_t idx = (size_t)row * ldc + col;
                    C[idx] = acc[mf][nf][r] + bias[col] + resid[idx];
                }
            }
    } else if (MODE == 5) {
        bf16* C = (bf16*)Cv;
#pragma unroll
        for (int mf = 0; mf < 8; mf++)
#pragma unroll
            for (int r = 0; r < 4; r++) {
                int row = rb0 + mf * 16 + quad * 4 + r;
#pragma unroll
                for (int nf = 0; nf < 4; nf++) {
                    int col = cb0 + nf * 16 + l15;
                    float v = acc[mf][nf][r] + bias[col];
                    C[(size_t)row * ldc + col] = (bf16)fmaxf(v, 0.f);
                }
            }
    } else if (MODE == 6) {
        float* C = (float*)Cv;
#pragma unroll
        for (int mf = 0; mf < 8; mf++)
#pragma unroll
            for (int r = 0; r < 4; r++) {
                int row = rb0 + mf * 16 + quad * 4 + r;
#pragma unroll
                for (int nf = 0; nf < 4; nf++) {
                    int col = cb0 + nf * 16 + l15;
                    size_t idx = (size_t)row * ldc + col;
                    float v = acc[mf][nf][r];
                    if (flags) v += bias[col];
                    C[idx] = C[idx] + v;
                }
            }
    }
}

// ---------------------------------------------------------------------------
// Fused QKV: A = h [M,E], B = Wqkv [3E, E] (contiguous q,k,v weights).
// tn 0..15 -> q, 16..31 -> k, 32..47 -> v (written transposed to vt[B,E,T]).
__global__ __launch_bounds__(256) void gemm_qkv(
    const bf16* __restrict__ A, const bf16* __restrict__ B,
    bf16* __restrict__ q, bf16* __restrict__ k, bf16* __restrict__ vt) {
    constexpr int BM = 128, BN = 128, BK = 32;
    int p = blockIdx.x + gridDim.x * blockIdx.y;   // grid (128, 48)
    int per = 32 * gridDim.y;
    int grp = p / per;
    int rem = p - grp * per;
    int tm = grp * 32 + (rem & 31);
    int tn = rem >> 5;

    __shared__ bf16 As[BM * BK];
    __shared__ bf16 Bs[BN * BK];
    __shared__ bf16 Tb[64 * 136];   // transpose staging (v path), two halves

    const int tid = threadIdx.x;
    const int wave = tid >> 6, lane = tid & 63;
    const int l15 = lane & 15, quad = lane >> 4;
    const int wm = wave >> 1, wn = wave & 1;

    const bf16* Ab = A + (size_t)tm * BM * E_;
    const bf16* Bb = B + (size_t)tn * BN * E_;

    f32x4 acc[4][4];
#pragma unroll
    for (int i = 0; i < 4; i++)
#pragma unroll
        for (int j = 0; j < 4; j++) { acc[i][j][0] = 0.f; acc[i][j][1] = 0.f; acc[i][j][2] = 0.f; acc[i][j][3] = 0.f; }

    const int srow = wave * 16 + (lane >> 2);
    const int scol = (lane & 3) * 8;

    for (int k0 = 0; k0 < E_; k0 += BK) {
#pragma unroll
        for (int u = 0; u < 2; u++) {
            gload_lds16(Ab + (size_t)(u * 64 + srow) * E_ + k0 + scol,
                        &As[(u * 64 + wave * 16) * BK]);
            gload_lds16(Bb + (size_t)(u * 64 + srow) * E_ + k0 + scol,
                        &Bs[(u * 64 + wave * 16) * BK]);
        }
        __syncthreads();
        bf16x8 af[4], bF[4];
#pragma unroll
        for (int mi = 0; mi < 4; mi++)
            af[mi] = *(const bf16x8*)&As[(wm * 64 + mi * 16 + l15) * BK + quad * 8];
#pragma unroll
        for (int ni = 0; ni < 4; ni++)
            bF[ni] = *(const bf16x8*)&Bs[(wn * 64 + ni * 16 + l15) * BK + quad * 8];
#pragma unroll
        for (int mi = 0; mi < 4; mi++)
#pragma unroll
            for (int ni = 0; ni < 4; ni++)
                acc[mi][ni] = __builtin_amdgcn_mfma_f32_16x16x32_bf16(af[mi], bF[ni], acc[mi][ni], 0, 0, 0);
        __syncthreads();
    }

    if (tn < 32) {
        bf16* C = (tn < 16) ? q : k;
        int cb = ((tn & 15) * BN) + wn * 64;
        int rbase = tm * BM + wm * 64;
#pragma unroll
        for (int mi = 0; mi < 4; mi++)
#pragma unroll
            for (int r = 0; r < 4; r++) {
                int row = rbase + mi * 16 + quad * 4 + r;
#pragma unroll
                for (int ni = 0; ni < 4; ni++) {
                    int col = cb + ni * 16 + l15;
                    C[(size_t)row * E_ + col] = (bf16)acc[mi][ni][r];
                }
            }
    } else {
        // v: transpose 128x128 tile in two 64-column halves through Tb
        int b = tm >> 4;                 // batch
        int tbase = (tm & 15) * 128;     // t offset within batch
        int nb = (tn - 32) * BN;         // head-dim block base
#pragma unroll
        for (int h = 0; h < 2; h++) {
            __syncthreads();
            if (wn == h) {
#pragma unroll
                for (int mi = 0; mi < 4; mi++)
#pragma unroll
                    for (int r = 0; r < 4; r++) {
                        int rl = wm * 64 + mi * 16 + quad * 4 + r;
#pragma unroll
                        for (int ni = 0; ni < 4; ni++) {
                            int cl = ni * 16 + l15;
                            Tb[cl * 136 + rl] = (bf16)acc[mi][ni][r];
                        }
                    }
            }
            __syncthreads();
#pragma unroll
            for (int pp = 0; pp < 4; pp++) {
                int cl = pp * 16 + (tid >> 4);
                int rch = (tid & 15) * 8;
                bf16x8 val = *(const bf16x8*)&Tb[cl * 136 + rch];
                int n = nb + h * 64 + cl;
                *(bf16x8*)&vt[(size_t)b * E_ * T_ + (size_t)n * T_ + tbase + rch] = val;
            }
        }
    }
}

// ---------------------------------------------------------------------------
extern "C" void kernel_launch(void* const* d_in, const int* in_sizes, int n_in,
                              void* d_out, int out_size, void* d_ws, size_t ws_size,
                              hipStream_t stream) {
    const float* x      = (const float*)d_in[0];
    const float* gamma1 = (const float*)d_in[1];
    const float* beta1  = (const float*)d_in[2];
    const float* Wq     = (const float*)d_in[3];
    const float* Wk     = (const float*)d_in[4];
    const float* Wv     = (const float*)d_in[5];
    const float* Wo     = (const float*)d_in[6];
    const float* bo     = (const float*)d_in[7];
    const float* gamma2 = (const float*)d_in[8];
    const float* beta2  = (const float*)d_in[9];
    const float* W1     = (const float*)d_in[10];
    const float* b1     = (const float*)d_in[11];
    const float* W2     = (const float*)d_in[12];
    const float* b2     = (const float*)d_in[13];
    float* out = (float*)d_out;

    char* ws = (char*)d_ws;
    const size_t SZ = (size_t)M_ * E_ * 2;     // 67,108,864 B
    bf16* hbf  = (bf16*)(ws + 0 * SZ);
    bf16* qbf  = (bf16*)(ws + 1 * SZ);
    bf16* kbf  = (bf16*)(ws + 2 * SZ);
    bf16* vt   = (bf16*)(ws + 3 * SZ);
    bf16* Sp   = (bf16*)(ws + 4 * SZ);         // [B,T,T] bf16
    bf16* attn = hbf;                          // reuse (h dead after QKV)
    bf16* h2   = qbf;                          // reuse (q dead after QK)
    bf16* ffb  = kbf;                          // reuse k+vt regions
    size_t woff = 5 * SZ;
    bf16* Wqb = (bf16*)(ws + woff); woff += (size_t)E_ * E_ * 2;
    bf16* Wkb = (bf16*)(ws + woff); woff += (size_t)E_ * E_ * 2;
    bf16* Wvb = (bf16*)(ws + woff); woff += (size_t)E_ * E_ * 2;
    bf16* Wob = (bf16*)(ws + woff); woff += (size_t)E_ * E_ * 2;
    bf16* W1b = (bf16*)(ws + woff); woff += (size_t)FF_ * E_ * 2;
    bf16* W2b = (bf16*)(ws + woff); woff += (size_t)FF_ * E_ * 2;

    cvt_kernel<<<2048, 256, 0, stream>>>(Wq, Wqb, E_ * E_ / 8);
    cvt_kernel<<<2048, 256, 0, stream>>>(Wk, Wkb, E_ * E_ / 8);
    cvt_kernel<<<2048, 256, 0, stream>>>(Wv, Wvb, E_ * E_ / 8);
    cvt_kernel<<<2048, 256, 0, stream>>>(Wo, Wob, E_ * E_ / 8);
    cvt_kernel<<<8192, 256, 0, stream>>>(W1, W1b, FF_ * E_ / 8);
    cvt_kernel<<<8192, 256, 0, stream>>>(W2, W2b, FF_ * E_ / 8);

    ln_kernel<<<M_, 256, 0, stream>>>(x, gamma1, beta1, hbf);

    dim3 blk(256);
    dim3 blk512(512);
    // fused QKV (Wqb/Wkb/Wvb are contiguous => one [3E,E] B matrix)
    dim3 gQKV(M_ / 128, 3 * E_ / 128, 1);   // (128, 48)
    gemm_qkv<<<gQKV, blk, 0, stream>>>(hbf, Wqb, qbf, kbf, vt);

    // QK^T (causal-skip), scaled
    dim3 gAttn(T_ / 128, T_ / 128, B_);     // (16,16,8)
    gemm_bt<1><<<gAttn, blk, 0, stream>>>(qbf, kbf, E_, E_, E_, T_,
                                          (long)T_ * E_, (long)T_ * E_, (long)T_ * T_,
                                          Sp, nullptr, nullptr, 0.022097086912079612f, 0);
    softmax_kernel<<<M_, 256, 0, stream>>>(Sp);
    // P @ V  (vt is [B, HS, T], K-contiguous)
    gemm_bt<3><<<gAttn, blk, 0, stream>>>(Sp, vt, T_, T_, T_, E_,
                                          (long)T_ * T_, (long)E_ * T_, (long)T_ * E_,
                                          attn, nullptr, nullptr, 1.f, 0);
    // out-projection + residual -> d_out (fp32)
    dim3 gProj(M_ / 256, E_ / 256, 1);      // (64, 8)
    gemm256<4><<<gProj, blk512, 0, stream>>>(attn, Wob, E_, E_, E_, E_,
                                             out, bo, x, 0);
    ln_kernel<<<M_, 256, 0, stream>>>(out, gamma2, beta2, h2);
    // FF in two 4096-wide slices
    dim3 gFF1(M_ / 256, 4096 / 256, 1);     // (64, 16)
    dim3 gFF2(M_ / 256, E_ / 256, 1);       // (64, 8)
    for (int s5 = 0; s5 < 2; s5++) {
        gemm256<5><<<gFF1, blk512, 0, stream>>>(h2, W1b + (size_t)s5 * 4096 * E_,
                                                E_, E_, E_, 4096,
                                                ffb, b1 + s5 * 4096, nullptr, 0);
        gemm256<6><<<gFF2, blk512, 0, stream>>>(ffb, W2b + s5 * 4096,
                                                4096, 4096, FF_, E_,
                                                out, b2, nullptr, s5 == 0 ? 1 : 0);
    }
}

// Round 2
// 2460.655 us; speedup vs baseline: 1.3441x; 1.1476x over previous
//
#include <hip/hip_runtime.h>
#include <cstdint>

typedef __bf16 bf16;
typedef __bf16 bf16x8 __attribute__((ext_vector_type(8)));
typedef float f32x4 __attribute__((ext_vector_type(4)));

#define B_  8
#define T_  2048
#define E_  2048
#define FF_ 8192
#define M_  (B_ * T_)   // 16384 rows total

// ---------------------------------------------------------------------------
__device__ __forceinline__ void gload_lds16(const void* g, void* l) {
    __builtin_amdgcn_global_load_lds(
        (const __attribute__((address_space(1))) uint32_t*)(uintptr_t)g,
        (__attribute__((address_space(3))) uint32_t*)(uintptr_t)l,
        16, 0, 0);
}

// ---------------------------------------------------------------------------
__global__ __launch_bounds__(256) void cvt_kernel(const float* __restrict__ src,
                                                  bf16* __restrict__ dst, int n8) {
    int i = blockIdx.x * 256 + threadIdx.x;
    if (i >= n8) return;
    const float4* s = (const float4*)src + (size_t)i * 2;
    float4 a = s[0], b = s[1];
    bf16x8 o;
    o[0] = (bf16)a.x; o[1] = (bf16)a.y; o[2] = (bf16)a.z; o[3] = (bf16)a.w;
    o[4] = (bf16)b.x; o[5] = (bf16)b.y; o[6] = (bf16)b.z; o[7] = (bf16)b.w;
    *(bf16x8*)&dst[(size_t)i * 8] = o;
}

// ---------------------------------------------------------------------------
__global__ __launch_bounds__(256) void ln_kernel(const float* __restrict__ x,
                                                 const float* __restrict__ gamma,
                                                 const float* __restrict__ beta,
                                                 bf16* __restrict__ out) {
    int row = blockIdx.x;
    int tid = threadIdx.x;
    const float* xr = x + (size_t)row * E_;
    float4 v0 = *(const float4*)&xr[tid * 8];
    float4 v1 = *(const float4*)&xr[tid * 8 + 4];
    float xs[8] = {v0.x, v0.y, v0.z, v0.w, v1.x, v1.y, v1.z, v1.w};
    float s = 0.f, s2 = 0.f;
#pragma unroll
    for (int j = 0; j < 8; j++) { s += xs[j]; s2 += xs[j] * xs[j]; }
#pragma unroll
    for (int o = 32; o > 0; o >>= 1) { s += __shfl_xor(s, o); s2 += __shfl_xor(s2, o); }
    __shared__ float red[8];
    int wave = tid >> 6, lane = tid & 63;
    if (lane == 0) { red[wave] = s; red[4 + wave] = s2; }
    __syncthreads();
    s  = red[0] + red[1] + red[2] + red[3];
    s2 = red[4] + red[5] + red[6] + red[7];
    float mean = s * (1.0f / E_);
    float var  = s2 * (1.0f / E_) - mean * mean;
    float rstd = rsqrtf(var + 1e-5f);
    float4 g0 = *(const float4*)&gamma[tid * 8];
    float4 g1 = *(const float4*)&gamma[tid * 8 + 4];
    float4 b0 = *(const float4*)&beta[tid * 8];
    float4 b1 = *(const float4*)&beta[tid * 8 + 4];
    float gs[8] = {g0.x, g0.y, g0.z, g0.w, g1.x, g1.y, g1.z, g1.w};
    float bs[8] = {b0.x, b0.y, b0.z, b0.w, b1.x, b1.y, b1.z, b1.w};
    bf16x8 o;
#pragma unroll
    for (int j = 0; j < 8; j++)
        o[j] = (bf16)((xs[j] - mean) * rstd * gs[j] + bs[j]);
    *(bf16x8*)&out[(size_t)row * E_ + tid * 8] = o;
}

// ---------------------------------------------------------------------------
// Zero-pads each causal row out to a 256 boundary (PV reads 256-wide K-tiles).
__global__ __launch_bounds__(256) void softmax_kernel(bf16* __restrict__ S) {
    int row = blockIdx.x;
    int b = row >> 11;
    int t = row & (T_ - 1);
    bf16* p = S + (size_t)b * T_ * T_ + (size_t)t * T_;
    int L = t + 1;
    int Lpad = ((t >> 8) + 1) << 8;
    int tid = threadIdx.x;
    int wave = tid >> 6, lane = tid & 63;
    float v[8];
    float m = -3.0e38f;
#pragma unroll
    for (int j = 0; j < 8; j++) {
        int s = tid + j * 256;
        v[j] = (s < L) ? (float)p[s] : -3.0e38f;
        m = fmaxf(m, v[j]);
    }
#pragma unroll
    for (int o = 32; o > 0; o >>= 1) m = fmaxf(m, __shfl_xor(m, o));
    __shared__ float red[8];
    if (lane == 0) red[wave] = m;
    __syncthreads();
    m = fmaxf(fmaxf(red[0], red[1]), fmaxf(red[2], red[3]));
    float sum = 0.f;
#pragma unroll
    for (int j = 0; j < 8; j++) {
        int s = tid + j * 256;
        float e = (s < L) ? __expf(v[j] - m) : 0.f;
        v[j] = e;
        sum += e;
    }
#pragma unroll
    for (int o = 32; o > 0; o >>= 1) sum += __shfl_xor(sum, o);
    if (lane == 0) red[4 + wave] = sum;
    __syncthreads();
    sum = red[4] + red[5] + red[6] + red[7];
    float inv = 1.0f / sum;
#pragma unroll
    for (int j = 0; j < 8; j++) {
        int s = tid + j * 256;
        if (s < Lpad) p[s] = (bf16)(v[j] * inv);
    }
}

// ---------------------------------------------------------------------------
// 64x64-tile bf16 transpose: src [b][t][h] -> dst [b][h][t]  (per batch 2048x2048)
__global__ __launch_bounds__(256) void transpose_kernel(const bf16* __restrict__ src,
                                                        bf16* __restrict__ dst) {
    __shared__ bf16 tb[64][72];   // stride 144 B (16B-aligned rows for b128 reads)
    int b  = blockIdx.z;
    int t0 = blockIdx.x * 64;
    int h0 = blockIdx.y * 64;
    const bf16* s = src + ((size_t)b * T_ + t0) * E_ + h0;
    bf16* d = dst + ((size_t)b * E_ + h0) * T_ + t0;
    int r  = threadIdx.x >> 3;        // 0..31
    int c8 = (threadIdx.x & 7) * 8;
#pragma unroll
    for (int p = 0; p < 2; p++) {
        bf16x8 v = *(const bf16x8*)&s[(size_t)(p * 32 + r) * E_ + c8];
#pragma unroll
        for (int j = 0; j < 8; j++) tb[c8 + j][p * 32 + r] = v[j];
    }
    __syncthreads();
#pragma unroll
    for (int p = 0; p < 2; p++) {
        bf16x8 v = *(const bf16x8*)&tb[p * 32 + r][c8];
        *(bf16x8*)&d[(size_t)(p * 32 + r) * T_ + c8] = v;
    }
}

// ---------------------------------------------------------------------------
// 256x256-tile, BK=64, 8-wave, 4-phase-per-K-tile GEMM (T2+T3+T4+T5 stack).
// C[M,N] = A[M,K] * B[N,K]^T
// MODE: 1 = QK^T: bf16 out * scale, causal tile skip, z-batch strides
//       3 = PV:   bf16 out, Keff = (tm+1)*256, z-batch strides
//       4 = fp32 out = acc + bias[col] + resid[idx]
//       5 = bf16 out = relu(acc + bias[col])
//       6 = fp32 out: C[idx] += acc + (flags ? bias[col] : 0)
//       7 = QKV: bf16 out into 3 segmented [M,2048] outputs (q|k|vtmp contiguous)
//
// LDS: lds[buf][A/B][half][khalf][128*32 bf16]  (8 KiB eighth-regions, 128 KiB total)
// Swizzle (both staging SOURCE and ds_read addr): b ^= (b>>4)&0x30  (st_16x32)
// Staging: 2 x global_load_lds_dwordx4 per phase; counted vmcnt(8) at P2/P4 only.
template <int MODE>
__global__ __launch_bounds__(512, 2) void gemm256(
    const bf16* __restrict__ A, const bf16* __restrict__ B,
    int K, int lda, int ldb, int ldc,
    long sA, long sB, long sC,
    void* __restrict__ Cv,
    const float* __restrict__ bias,
    const float* __restrict__ resid,
    float scale, int flags) {
    __shared__ bf16 lds[2][2][2][2][4096];

    const int tid  = threadIdx.x;
    const int lane = tid & 63;
    const int l15  = lane & 15, quad = lane >> 4;
    const int wave = tid >> 6;
    const int wm = wave >> 2;         // 0..1  (M half)
    const int wn = wave & 3;          // 0..3  (N quarter)
    const int bh = wn >> 1, bq = wn & 1;

    const int bz = blockIdx.z;
    int tm_, tn_;
    if (MODE == 1 || MODE == 3) {
        tm_ = blockIdx.x; tn_ = blockIdx.y;
        if (MODE == 1 && tn_ > tm_) return;
    } else {
        // XCD-bijective block swizzle (nwg % 8 == 0 for all call sites)
        int p   = blockIdx.x + gridDim.x * blockIdx.y;
        int nwg = gridDim.x * gridDim.y;
        int cpx = nwg >> 3;
        int w   = (p & 7) * cpx + (p >> 3);
        tn_ = w % gridDim.y;
        tm_ = w / gridDim.y;
    }

    int Keff = K;
    if (MODE == 3) Keff = min(K, (tm_ + 1) * 256);
    const int NT = Keff >> 6;         // K-tiles of 64 (always even at call sites)

    // staging geometry: dest byte d = tid*16 (linear), source = swz(d)
    int d    = tid * 16;
    int lsw  = d ^ ((d >> 4) & 0x30);
    int srow = lsw >> 6;              // 0..127
    int ske  = (lsw & 63) >> 1;       // 0,8,16,24
    int wq   = wave * 1024;           // wave-uniform LDS byte offset

    const bf16* As0 = A + sA * bz + (size_t)(tm_ * 256 + srow) * lda + ske;
    const bf16* As1 = As0 + (size_t)128 * lda;
    const bf16* Bs0 = B + sB * bz + (size_t)(tn_ * 256 + srow) * ldb + ske;
    const bf16* Bs1 = Bs0 + (size_t)128 * ldb;

    // ds_read per-thread offset (swizzle folds to a per-thread constant)
    const int roff = (l15 * 64 + quad * 16) ^ ((l15 & 12) << 2);

    f32x4 acc[8][4];
#pragma unroll
    for (int i = 0; i < 8; i++)
#pragma unroll
        for (int j = 0; j < 4; j++) {
            acc[i][j][0] = 0.f; acc[i][j][1] = 0.f; acc[i][j][2] = 0.f; acc[i][j][3] = 0.f;
        }

    bf16x8 bfr[4];

#define STG(P0, P1, CB, R0, R1)                                                        \
    do {                                                                               \
        gload_lds16((P0) + (CB), (char*)(R0) + wq);                                    \
        gload_lds16((P1) + (CB), (char*)(R1) + wq);                                    \
    } while (0)

    // prologue: tile0 k0 (A,B), tile0 k1 (A,B), tile1 k0 (A,B) = 12 loads
    STG(As0, As1, 0,  &lds[0][0][0][0][0], &lds[0][0][1][0][0]);
    STG(Bs0, Bs1, 0,  &lds[0][1][0][0][0], &lds[0][1][1][0][0]);
    STG(As0, As1, 32, &lds[0][0][0][1][0], &lds[0][0][1][1][0]);
    STG(Bs0, Bs1, 32, &lds[0][1][0][1][0], &lds[0][1][1][1][0]);
    STG(As0, As1, 64, &lds[1][0][0][0][0], &lds[1][0][1][0][0]);
    STG(Bs0, Bs1, 64, &lds[1][1][0][0][0], &lds[1][1][1][0][0]);
    asm volatile("s_waitcnt vmcnt(8)" ::: "memory");   // retire tile0 k0
    __builtin_amdgcn_s_barrier();

#define PH(Q, KK, H, DOB, SP0, SP1, SCB, SR0, SR1, DOVM)                               \
    do {                                                                               \
        const char* ar_ = (const char*)&lds[(Q)][0][wm][(KK)][0] + (H) * 4096 + roff;  \
        bf16x8 a_[4];                                                                  \
        _Pragma("unroll")                                                              \
        for (int mi = 0; mi < 4; mi++)                                                 \
            a_[mi] = *(const bf16x8*)(ar_ + mi * 1024);                                \
        if (DOB) {                                                                     \
            const char* br_ = (const char*)&lds[(Q)][1][bh][(KK)][0] + bq * 4096 + roff; \
            _Pragma("unroll")                                                          \
            for (int ni = 0; ni < 4; ni++)                                             \
                bfr[ni] = *(const bf16x8*)(br_ + ni * 1024);                           \
        }                                                                              \
        STG(SP0, SP1, SCB, SR0, SR1);                                                  \
        __builtin_amdgcn_s_barrier();                                                  \
        __builtin_amdgcn_s_setprio(1);                                                 \
        _Pragma("unroll")                                                              \
        for (int mi = 0; mi < 4; mi++)                                                 \
            _Pragma("unroll")                                                          \
            for (int ni = 0; ni < 4; ni++)                                             \
                acc[(H) * 4 + mi][ni] = __builtin_amdgcn_mfma_f32_16x16x32_bf16(       \
                    a_[mi], bfr[ni], acc[(H) * 4 + mi][ni], 0, 0, 0);                  \
        __builtin_amdgcn_s_setprio(0);                                                 \
        if (DOVM) asm volatile("s_waitcnt vmcnt(8)" ::: "memory");                     \
        __builtin_amdgcn_s_barrier();                                                  \
    } while (0)

    // tile u in buf Q; stage u+1's k1 (P1:A, P2:B -> buf Q^1) and
    // u+2's k0 (P3:A, P4:B -> buf Q). Counted vmcnt(8) at P2/P4.
#define TILE(Q, WS1, WS2)                                                                              \
    do {                                                                                               \
        PH(Q, 0, 0, 1, As0, As1, (WS1) * 64 + 32, &lds[(Q) ^ 1][0][0][1][0], &lds[(Q) ^ 1][0][1][1][0], 0); \
        PH(Q, 0, 1, 0, Bs0, Bs1, (WS1) * 64 + 32, &lds[(Q) ^ 1][1][0][1][0], &lds[(Q) ^ 1][1][1][1][0], 1); \
        PH(Q, 1, 0, 1, As0, As1, (WS2) * 64, &lds[(Q)][0][0][0][0], &lds[(Q)][0][1][0][0], 0);         \
        PH(Q, 1, 1, 0, Bs0, Bs1, (WS2) * 64, &lds[(Q)][1][0][0][0], &lds[(Q)][1][1][0][0], 1);         \
    } while (0)

    for (int t = 0; t < NT; t += 2) {
        int wa = t + 1;                               // tile t stages (t+1).k1
        int wb = (t + 2 < NT) ? t + 2 : NT - 1;       // tile t stages (t+2).k0 ; tile t+1 stages (t+2).k1
        int wd = (t + 3 < NT) ? t + 3 : NT - 1;       // tile t+1 stages (t+3).k0
        TILE(0, wa, wb);
        TILE(1, wb, wd);
    }
    asm volatile("s_waitcnt vmcnt(0)" ::: "memory");

#undef TILE
#undef PH
#undef STG

    // epilogue
    const int rb0 = tm_ * 256 + wm * 128;
    const int cb0 = tn_ * 256 + wn * 64;
    if (MODE == 1 || MODE == 3) {
        bf16* C = (bf16*)Cv + sC * bz;
#pragma unroll
        for (int mf = 0; mf < 8; mf++)
#pragma unroll
            for (int r = 0; r < 4; r++) {
                int row = rb0 + mf * 16 + quad * 4 + r;
#pragma unroll
                for (int nf = 0; nf < 4; nf++) {
                    int col = cb0 + nf * 16 + l15;
                    C[(size_t)row * ldc + col] = (bf16)(acc[mf][nf][r] * scale);
                }
            }
    } else if (MODE == 7) {
        bf16* C = (bf16*)Cv + (size_t)(cb0 >> 11) * M_ * E_;
        int cB = cb0 & 2047;
#pragma unroll
        for (int mf = 0; mf < 8; mf++)
#pragma unroll
            for (int r = 0; r < 4; r++) {
                int row = rb0 + mf * 16 + quad * 4 + r;
#pragma unroll
                for (int nf = 0; nf < 4; nf++) {
                    int col = cB + nf * 16 + l15;
                    C[(size_t)row * ldc + col] = (bf16)acc[mf][nf][r];
                }
            }
    } else if (MODE == 4) {
        float* C = (float*)Cv;
#pragma unroll
        for (int mf = 0; mf < 8; mf++)
#pragma unroll
            for (int r = 0; r < 4; r++) {
                int row = rb0 + mf * 16 + quad * 4 + r;
#pragma unroll
                for (int nf = 0; nf < 4; nf++) {
                    int col = cb0 + nf * 16 + l15;
                    size_t idx = (size_t)row * ldc + col;
                    C[idx] = acc[mf][nf][r] + bias[col] + resid[idx];
                }
            }
    } else if (MODE == 5) {
        bf16* C = (bf16*)Cv;
#pragma unroll
        for (int mf = 0; mf < 8; mf++)
#pragma unroll
            for (int r = 0; r < 4; r++) {
                int row = rb0 + mf * 16 + quad * 4 + r;
#pragma unroll
                for (int nf = 0; nf < 4; nf++) {
                    int col = cb0 + nf * 16 + l15;
                    float v = acc[mf][nf][r] + bias[col];
                    C[(size_t)row * ldc + col] = (bf16)fmaxf(v, 0.f);
                }
            }
    } else if (MODE == 6) {
        float* C = (float*)Cv;
#pragma unroll
        for (int mf = 0; mf < 8; mf++)
#pragma unroll
            for (int r = 0; r < 4; r++) {
                int row = rb0 + mf * 16 + quad * 4 + r;
#pragma unroll
                for (int nf = 0; nf < 4; nf++) {
                    int col = cb0 + nf * 16 + l15;
                    size_t idx = (size_t)row * ldc + col;
                    float v = acc[mf][nf][r];
                    if (flags) v += bias[col];
                    C[idx] = C[idx] + v;
                }
            }
    }
}

// ---------------------------------------------------------------------------
extern "C" void kernel_launch(void* const* d_in, const int* in_sizes, int n_in,
                              void* d_out, int out_size, void* d_ws, size_t ws_size,
                              hipStream_t stream) {
    const float* x      = (const float*)d_in[0];
    const float* gamma1 = (const float*)d_in[1];
    const float* beta1  = (const float*)d_in[2];
    const float* Wq     = (const float*)d_in[3];
    const float* Wk     = (const float*)d_in[4];
    const float* Wv     = (const float*)d_in[5];
    const float* Wo     = (const float*)d_in[6];
    const float* bo     = (const float*)d_in[7];
    const float* gamma2 = (const float*)d_in[8];
    const float* beta2  = (const float*)d_in[9];
    const float* W1     = (const float*)d_in[10];
    const float* b1     = (const float*)d_in[11];
    const float* W2     = (const float*)d_in[12];
    const float* b2     = (const float*)d_in[13];
    float* out = (float*)d_out;

    char* ws = (char*)d_ws;
    const size_t SZ = (size_t)M_ * E_ * 2;     // 67,108,864 B
    // slot lifetimes:
    //  slot0: hbf (LN1->QKV)        then vt   (transpose->PV)
    //  slot1: qbf (QKV->QK^T)       then h2   (LN2->FF)
    //  slot2: kbf (QKV->QK^T)       then ffb lower half (FF)
    //  slot3: vtmp (QKV->transpose) then attn (PV->proj), then ffb upper half
    //  slot4: Sp (QK^T->PV)
    bf16* hbf  = (bf16*)(ws + 0 * SZ);
    bf16* vt   = (bf16*)(ws + 0 * SZ);
    bf16* qbf  = (bf16*)(ws + 1 * SZ);
    bf16* kbf  = (bf16*)(ws + 2 * SZ);
    bf16* vtmp = (bf16*)(ws + 3 * SZ);
    bf16* Sp   = (bf16*)(ws + 4 * SZ);
    bf16* attn = vtmp;
    bf16* h2   = qbf;
    bf16* ffb  = kbf;                          // spans slots 2+3
    size_t woff = 5 * SZ;
    bf16* Wqb = (bf16*)(ws + woff); woff += (size_t)E_ * E_ * 2;
    bf16* Wkb = (bf16*)(ws + woff); woff += (size_t)E_ * E_ * 2;
    bf16* Wvb = (bf16*)(ws + woff); woff += (size_t)E_ * E_ * 2;
    bf16* Wob = (bf16*)(ws + woff); woff += (size_t)E_ * E_ * 2;
    bf16* W1b = (bf16*)(ws + woff); woff += (size_t)FF_ * E_ * 2;
    bf16* W2b = (bf16*)(ws + woff); woff += (size_t)FF_ * E_ * 2;

    cvt_kernel<<<2048, 256, 0, stream>>>(Wq, Wqb, E_ * E_ / 8);
    cvt_kernel<<<2048, 256, 0, stream>>>(Wk, Wkb, E_ * E_ / 8);
    cvt_kernel<<<2048, 256, 0, stream>>>(Wv, Wvb, E_ * E_ / 8);
    cvt_kernel<<<2048, 256, 0, stream>>>(Wo, Wob, E_ * E_ / 8);
    cvt_kernel<<<8192, 256, 0, stream>>>(W1, W1b, FF_ * E_ / 8);
    cvt_kernel<<<8192, 256, 0, stream>>>(W2, W2b, FF_ * E_ / 8);

    ln_kernel<<<M_, 256, 0, stream>>>(x, gamma1, beta1, hbf);

    dim3 blk512(512);
    // fused QKV: one [6144, E] weight matrix; outputs q|k|vtmp (contiguous slots)
    dim3 gQKV(M_ / 256, 3 * E_ / 256, 1);   // (64, 24)
    gemm256<7><<<gQKV, blk512, 0, stream>>>(hbf, Wqb, E_, E_, E_, E_, 0, 0, 0,
                                            qbf, nullptr, nullptr, 1.f, 0);
    // v transpose: vtmp [b][t][h] -> vt [b][h][t]
    dim3 gT(T_ / 64, E_ / 64, B_);          // (32, 32, 8)
    transpose_kernel<<<gT, 256, 0, stream>>>(vtmp, vt);

    // QK^T (causal-skip), scaled
    dim3 gAttn(T_ / 256, T_ / 256, B_);     // (8, 8, 8)
    gemm256<1><<<gAttn, blk512, 0, stream>>>(qbf, kbf, E_, E_, E_, T_,
                                             (long)T_ * E_, (long)T_ * E_, (long)T_ * T_,
                                             Sp, nullptr, nullptr, 0.022097086912079612f, 0);
    softmax_kernel<<<M_, 256, 0, stream>>>(Sp);
    // P @ V  (vt is [B, HS, T], K-contiguous)
    gemm256<3><<<gAttn, blk512, 0, stream>>>(Sp, vt, T_, T_, T_, E_,
                                             (long)T_ * T_, (long)E_ * T_, (long)T_ * E_,
                                             attn, nullptr, nullptr, 1.f, 0);
    // out-projection + residual -> d_out (fp32)
    dim3 gProj(M_ / 256, E_ / 256, 1);      // (64, 8)
    gemm256<4><<<gProj, blk512, 0, stream>>>(attn, Wob, E_, E_, E_, E_, 0, 0, 0,
                                             out, bo, x, 1.f, 0);
    ln_kernel<<<M_, 256, 0, stream>>>(out, gamma2, beta2, h2);
    // FF in two 4096-wide slices
    dim3 gFF1(M_ / 256, 4096 / 256, 1);     // (64, 16)
    dim3 gFF2(M_ / 256, E_ / 256, 1);       // (64, 8)
    for (int s5 = 0; s5 < 2; s5++) {
        gemm256<5><<<gFF1, blk512, 0, stream>>>(h2, W1b + (size_t)s5 * 4096 * E_,
                                                E_, E_, E_, 4096, 0, 0, 0,
                                                ffb, b1 + s5 * 4096, nullptr, 1.f, 0);
        gemm256<6><<<gFF2, blk512, 0, stream>>>(ffb, W2b + s5 * 4096,
                                                4096, 4096, FF_, E_, 0, 0, 0,
                                                out, b2, nullptr, 1.f, s5 == 0 ? 1 : 0);
    }
}

// Round 3
// 2383.918 us; speedup vs baseline: 1.3874x; 1.0322x over previous
//
#include <hip/hip_runtime.h>
#include <cstdint>

typedef __bf16 bf16;
typedef __bf16 bf16x8 __attribute__((ext_vector_type(8)));
typedef float f32x4 __attribute__((ext_vector_type(4)));

#define B_  8
#define T_  2048
#define E_  2048
#define FF_ 8192
#define M_  (B_ * T_)   // 16384 rows total

// ---------------------------------------------------------------------------
__device__ __forceinline__ void gload_lds16(const void* g, void* l) {
    __builtin_amdgcn_global_load_lds(
        (const __attribute__((address_space(1))) uint32_t*)(uintptr_t)g,
        (__attribute__((address_space(3))) uint32_t*)(uintptr_t)l,
        16, 0, 0);
}

// ---------------------------------------------------------------------------
__global__ __launch_bounds__(256) void cvt_kernel(const float* __restrict__ src,
                                                  bf16* __restrict__ dst, int n8) {
    int i = blockIdx.x * 256 + threadIdx.x;
    if (i >= n8) return;
    const float4* s = (const float4*)src + (size_t)i * 2;
    float4 a = s[0], b = s[1];
    bf16x8 o;
    o[0] = (bf16)a.x; o[1] = (bf16)a.y; o[2] = (bf16)a.z; o[3] = (bf16)a.w;
    o[4] = (bf16)b.x; o[5] = (bf16)b.y; o[6] = (bf16)b.z; o[7] = (bf16)b.w;
    *(bf16x8*)&dst[(size_t)i * 8] = o;
}

// ---------------------------------------------------------------------------
__global__ __launch_bounds__(256) void ln_kernel(const float* __restrict__ x,
                                                 const float* __restrict__ gamma,
                                                 const float* __restrict__ beta,
                                                 bf16* __restrict__ out) {
    int row = blockIdx.x;
    int tid = threadIdx.x;
    const float* xr = x + (size_t)row * E_;
    float4 v0 = *(const float4*)&xr[tid * 8];
    float4 v1 = *(const float4*)&xr[tid * 8 + 4];
    float xs[8] = {v0.x, v0.y, v0.z, v0.w, v1.x, v1.y, v1.z, v1.w};
    float s = 0.f, s2 = 0.f;
#pragma unroll
    for (int j = 0; j < 8; j++) { s += xs[j]; s2 += xs[j] * xs[j]; }
#pragma unroll
    for (int o = 32; o > 0; o >>= 1) { s += __shfl_xor(s, o); s2 += __shfl_xor(s2, o); }
    __shared__ float red[8];
    int wave = tid >> 6, lane = tid & 63;
    if (lane == 0) { red[wave] = s; red[4 + wave] = s2; }
    __syncthreads();
    s  = red[0] + red[1] + red[2] + red[3];
    s2 = red[4] + red[5] + red[6] + red[7];
    float mean = s * (1.0f / E_);
    float var  = s2 * (1.0f / E_) - mean * mean;
    float rstd = rsqrtf(var + 1e-5f);
    float4 g0 = *(const float4*)&gamma[tid * 8];
    float4 g1 = *(const float4*)&gamma[tid * 8 + 4];
    float4 b0 = *(const float4*)&beta[tid * 8];
    float4 b1 = *(const float4*)&beta[tid * 8 + 4];
    float gs[8] = {g0.x, g0.y, g0.z, g0.w, g1.x, g1.y, g1.z, g1.w};
    float bs[8] = {b0.x, b0.y, b0.z, b0.w, b1.x, b1.y, b1.z, b1.w};
    bf16x8 o;
#pragma unroll
    for (int j = 0; j < 8; j++)
        o[j] = (bf16)((xs[j] - mean) * rstd * gs[j] + bs[j]);
    *(bf16x8*)&out[(size_t)row * E_ + tid * 8] = o;
}

// ---------------------------------------------------------------------------
// Zero-pads each causal row out to a 256 boundary (PV reads 256-wide K-tiles).
__global__ __launch_bounds__(256) void softmax_kernel(bf16* __restrict__ S) {
    int row = blockIdx.x;
    int b = row >> 11;
    int t = row & (T_ - 1);
    bf16* p = S + (size_t)b * T_ * T_ + (size_t)t * T_;
    int L = t + 1;
    int Lpad = ((t >> 8) + 1) << 8;
    int tid = threadIdx.x;
    int wave = tid >> 6, lane = tid & 63;
    float v[8];
    float m = -3.0e38f;
#pragma unroll
    for (int j = 0; j < 8; j++) {
        int s = tid + j * 256;
        v[j] = (s < L) ? (float)p[s] : -3.0e38f;
        m = fmaxf(m, v[j]);
    }
#pragma unroll
    for (int o = 32; o > 0; o >>= 1) m = fmaxf(m, __shfl_xor(m, o));
    __shared__ float red[8];
    if (lane == 0) red[wave] = m;
    __syncthreads();
    m = fmaxf(fmaxf(red[0], red[1]), fmaxf(red[2], red[3]));
    float sum = 0.f;
#pragma unroll
    for (int j = 0; j < 8; j++) {
        int s = tid + j * 256;
        float e = (s < L) ? __expf(v[j] - m) : 0.f;
        v[j] = e;
        sum += e;
    }
#pragma unroll
    for (int o = 32; o > 0; o >>= 1) sum += __shfl_xor(sum, o);
    if (lane == 0) red[4 + wave] = sum;
    __syncthreads();
    sum = red[4] + red[5] + red[6] + red[7];
    float inv = 1.0f / sum;
#pragma unroll
    for (int j = 0; j < 8; j++) {
        int s = tid + j * 256;
        if (s < Lpad) p[s] = (bf16)(v[j] * inv);
    }
}

// ---------------------------------------------------------------------------
// 64x64-tile bf16 transpose: src [b][t][h] -> dst [b][h][t]  (per batch 2048x2048)
__global__ __launch_bounds__(256) void transpose_kernel(const bf16* __restrict__ src,
                                                        bf16* __restrict__ dst) {
    __shared__ bf16 tb[64][72];   // stride 144 B (16B-aligned rows for b128 reads)
    int b  = blockIdx.z;
    int t0 = blockIdx.x * 64;
    int h0 = blockIdx.y * 64;
    const bf16* s = src + ((size_t)b * T_ + t0) * E_ + h0;
    bf16* d = dst + ((size_t)b * E_ + h0) * T_ + t0;
    int r  = threadIdx.x >> 3;        // 0..31
    int c8 = (threadIdx.x & 7) * 8;
#pragma unroll
    for (int p = 0; p < 2; p++) {
        bf16x8 v = *(const bf16x8*)&s[(size_t)(p * 32 + r) * E_ + c8];
#pragma unroll
        for (int j = 0; j < 8; j++) tb[c8 + j][p * 32 + r] = v[j];
    }
    __syncthreads();
#pragma unroll
    for (int p = 0; p < 2; p++) {
        bf16x8 v = *(const bf16x8*)&tb[p * 32 + r][c8];
        *(bf16x8*)&d[(size_t)(p * 32 + r) * T_ + c8] = v;
    }
}

// ---------------------------------------------------------------------------
// 256x256-tile, BK=64, 8-wave, 4-phase-per-K-tile GEMM (T2+T3+T4+T5 stack).
// C[M,N] = A[M,K] * B[N,K]^T
// MODE: 1 = QK^T: bf16 out * scale, causal tile skip, z-batch strides
//       3 = PV:   bf16 out, Keff = (tm+1)*256, z-batch strides
//       4 = fp32 out = acc + bias[col] + resid[idx]
//       5 = bf16 out = relu(acc + bias[col])
//       6 = fp32 out: C[idx] += acc + (flags ? bias[col] : 0)
//       7 = QKV: bf16 out into 3 segmented [M,2048] outputs (q|k|vtmp contiguous)
//
// LDS: lds[buf][A/B][half][khalf][128*32 bf16]  (8 KiB eighth-regions, 128 KiB total)
// Swizzle: byte bits[5:4] ^= bits[8:7]  (slot = quad ^ ((row>>1)&3)) — applied to
// BOTH staging SOURCE address and ds_read address (involution, 16B-granular).
// Per 8-lane service group this tiles all 32 banks exactly once (conflict-free).
// Staging: 2 x global_load_lds_dwordx4 per phase; counted vmcnt(8) at P2/P4 only.
template <int MODE>
__global__ __launch_bounds__(512, 2) void gemm256(
    const bf16* __restrict__ A, const bf16* __restrict__ B,
    int K, int lda, int ldb, int ldc,
    long sA, long sB, long sC,
    void* __restrict__ Cv,
    const float* __restrict__ bias,
    const float* __restrict__ resid,
    float scale, int flags) {
    __shared__ bf16 lds[2][2][2][2][4096];

    const int tid  = threadIdx.x;
    const int lane = tid & 63;
    const int l15  = lane & 15, quad = lane >> 4;
    const int wave = tid >> 6;
    const int wm = wave >> 2;         // 0..1  (M half)
    const int wn = wave & 3;          // 0..3  (N quarter)
    const int bh = wn >> 1, bq = wn & 1;

    const int bz = blockIdx.z;
    int tm_, tn_;
    if (MODE == 1 || MODE == 3) {
        tm_ = blockIdx.x; tn_ = blockIdx.y;
        if (MODE == 1 && tn_ > tm_) return;
    } else {
        // XCD-bijective block swizzle (nwg % 8 == 0 for all call sites)
        int p   = blockIdx.x + gridDim.x * blockIdx.y;
        int nwg = gridDim.x * gridDim.y;
        int cpx = nwg >> 3;
        int w   = (p & 7) * cpx + (p >> 3);
        tn_ = w % gridDim.y;
        tm_ = w / gridDim.y;
    }

    int Keff = K;
    if (MODE == 3) Keff = min(K, (tm_ + 1) * 256);
    const int NT = Keff >> 6;         // K-tiles of 64 (always even at call sites)

    // staging geometry: dest byte d = tid*16 (linear), source = swz(d)
    int d    = tid * 16;
    int lsw  = d ^ ((d >> 3) & 0x30);
    int srow = lsw >> 6;              // 0..127
    int ske  = (lsw & 63) >> 1;       // element offset within 32-wide k-slice
    int wq   = wave * 1024;           // wave-uniform LDS byte offset

    const bf16* As0 = A + sA * bz + (size_t)(tm_ * 256 + srow) * lda + ske;
    const bf16* As1 = As0 + (size_t)128 * lda;
    const bf16* Bs0 = B + sB * bz + (size_t)(tn_ * 256 + srow) * ldb + ske;
    const bf16* Bs1 = Bs0 + (size_t)128 * ldb;

    // ds_read per-thread offset (swizzle folds to a per-thread constant)
    const int roff = (l15 * 64 + quad * 16) ^ ((l15 & 6) << 3);

    f32x4 acc[8][4];
#pragma unroll
    for (int i = 0; i < 8; i++)
#pragma unroll
        for (int j = 0; j < 4; j++) {
            acc[i][j][0] = 0.f; acc[i][j][1] = 0.f; acc[i][j][2] = 0.f; acc[i][j][3] = 0.f;
        }

    bf16x8 bfr[4];

#define STG(P0, P1, CB, R0, R1)                                                        \
    do {                                                                               \
        gload_lds16((P0) + (CB), (char*)(R0) + wq);                                    \
        gload_lds16((P1) + (CB), (char*)(R1) + wq);                                    \
    } while (0)

    // prologue: tile0 k0 (A,B), tile0 k1 (A,B), tile1 k0 (A,B) = 12 loads
    STG(As0, As1, 0,  &lds[0][0][0][0][0], &lds[0][0][1][0][0]);
    STG(Bs0, Bs1, 0,  &lds[0][1][0][0][0], &lds[0][1][1][0][0]);
    STG(As0, As1, 32, &lds[0][0][0][1][0], &lds[0][0][1][1][0]);
    STG(Bs0, Bs1, 32, &lds[0][1][0][1][0], &lds[0][1][1][1][0]);
    STG(As0, As1, 64, &lds[1][0][0][0][0], &lds[1][0][1][0][0]);
    STG(Bs0, Bs1, 64, &lds[1][1][0][0][0], &lds[1][1][1][0][0]);
    asm volatile("s_waitcnt vmcnt(8)" ::: "memory");   // retire tile0 k0
    __builtin_amdgcn_s_barrier();

#define PH(Q, KK, H, DOB, SP0, SP1, SCB, SR0, SR1, DOVM)                               \
    do {                                                                               \
        const char* ar_ = (const char*)&lds[(Q)][0][wm][(KK)][0] + (H) * 4096 + roff;  \
        bf16x8 a_[4];                                                                  \
        _Pragma("unroll")                                                              \
        for (int mi = 0; mi < 4; mi++)                                                 \
            a_[mi] = *(const bf16x8*)(ar_ + mi * 1024);                                \
        if (DOB) {                                                                     \
            const char* br_ = (const char*)&lds[(Q)][1][bh][(KK)][0] + bq * 4096 + roff; \
            _Pragma("unroll")                                                          \
            for (int ni = 0; ni < 4; ni++)                                             \
                bfr[ni] = *(const bf16x8*)(br_ + ni * 1024);                           \
        }                                                                              \
        STG(SP0, SP1, SCB, SR0, SR1);                                                  \
        __builtin_amdgcn_s_barrier();                                                  \
        __builtin_amdgcn_s_setprio(1);                                                 \
        _Pragma("unroll")                                                              \
        for (int mi = 0; mi < 4; mi++)                                                 \
            _Pragma("unroll")                                                          \
            for (int ni = 0; ni < 4; ni++)                                             \
                acc[(H) * 4 + mi][ni] = __builtin_amdgcn_mfma_f32_16x16x32_bf16(       \
                    a_[mi], bfr[ni], acc[(H) * 4 + mi][ni], 0, 0, 0);                  \
        __builtin_amdgcn_s_setprio(0);                                                 \
        if (DOVM) asm volatile("s_waitcnt vmcnt(8)" ::: "memory");                     \
        __builtin_amdgcn_s_barrier();                                                  \
    } while (0)

    // tile u in buf Q; stage u+1's k1 (P1:A, P2:B -> buf Q^1) and
    // u+2's k0 (P3:A, P4:B -> buf Q). Counted vmcnt(8) at P2/P4.
#define TILE(Q, WS1, WS2)                                                                              \
    do {                                                                                               \
        PH(Q, 0, 0, 1, As0, As1, (WS1) * 64 + 32, &lds[(Q) ^ 1][0][0][1][0], &lds[(Q) ^ 1][0][1][1][0], 0); \
        PH(Q, 0, 1, 0, Bs0, Bs1, (WS1) * 64 + 32, &lds[(Q) ^ 1][1][0][1][0], &lds[(Q) ^ 1][1][1][1][0], 1); \
        PH(Q, 1, 0, 1, As0, As1, (WS2) * 64, &lds[(Q)][0][0][0][0], &lds[(Q)][0][1][0][0], 0);         \
        PH(Q, 1, 1, 0, Bs0, Bs1, (WS2) * 64, &lds[(Q)][1][0][0][0], &lds[(Q)][1][1][0][0], 1);         \
    } while (0)

    for (int t = 0; t < NT; t += 2) {
        int wa = t + 1;                               // tile t stages (t+1).k1
        int wb = (t + 2 < NT) ? t + 2 : NT - 1;       // tile t stages (t+2).k0 ; tile t+1 stages (t+2).k1
        int wd = (t + 3 < NT) ? t + 3 : NT - 1;       // tile t+1 stages (t+3).k0
        TILE(0, wa, wb);
        TILE(1, wb, wd);
    }
    asm volatile("s_waitcnt vmcnt(0)" ::: "memory");

#undef TILE
#undef PH
#undef STG

    // epilogue
    const int rb0 = tm_ * 256 + wm * 128;
    const int cb0 = tn_ * 256 + wn * 64;
    if (MODE == 1 || MODE == 3) {
        bf16* C = (bf16*)Cv + sC * bz;
#pragma unroll
        for (int mf = 0; mf < 8; mf++)
#pragma unroll
            for (int r = 0; r < 4; r++) {
                int row = rb0 + mf * 16 + quad * 4 + r;
#pragma unroll
                for (int nf = 0; nf < 4; nf++) {
                    int col = cb0 + nf * 16 + l15;
                    C[(size_t)row * ldc + col] = (bf16)(acc[mf][nf][r] * scale);
                }
            }
    } else if (MODE == 7) {
        bf16* C = (bf16*)Cv + (size_t)(cb0 >> 11) * M_ * E_;
        int cB = cb0 & 2047;
#pragma unroll
        for (int mf = 0; mf < 8; mf++)
#pragma unroll
            for (int r = 0; r < 4; r++) {
                int row = rb0 + mf * 16 + quad * 4 + r;
#pragma unroll
                for (int nf = 0; nf < 4; nf++) {
                    int col = cB + nf * 16 + l15;
                    C[(size_t)row * ldc + col] = (bf16)acc[mf][nf][r];
                }
            }
    } else if (MODE == 4) {
        float* C = (float*)Cv;
#pragma unroll
        for (int mf = 0; mf < 8; mf++)
#pragma unroll
            for (int r = 0; r < 4; r++) {
                int row = rb0 + mf * 16 + quad * 4 + r;
#pragma unroll
                for (int nf = 0; nf < 4; nf++) {
                    int col = cb0 + nf * 16 + l15;
                    size_t idx = (size_t)row * ldc + col;
                    C[idx] = acc[mf][nf][r] + bias[col] + resid[idx];
                }
            }
    } else if (MODE == 5) {
        bf16* C = (bf16*)Cv;
#pragma unroll
        for (int mf = 0; mf < 8; mf++)
#pragma unroll
            for (int r = 0; r < 4; r++) {
                int row = rb0 + mf * 16 + quad * 4 + r;
#pragma unroll
                for (int nf = 0; nf < 4; nf++) {
                    int col = cb0 + nf * 16 + l15;
                    float v = acc[mf][nf][r] + bias[col];
                    C[(size_t)row * ldc + col] = (bf16)fmaxf(v, 0.f);
                }
            }
    } else if (MODE == 6) {
        float* C = (float*)Cv;
#pragma unroll
        for (int mf = 0; mf < 8; mf++)
#pragma unroll
            for (int r = 0; r < 4; r++) {
                int row = rb0 + mf * 16 + quad * 4 + r;
#pragma unroll
                for (int nf = 0; nf < 4; nf++) {
                    int col = cb0 + nf * 16 + l15;
                    size_t idx = (size_t)row * ldc + col;
                    float v = acc[mf][nf][r];
                    if (flags) v += bias[col];
                    C[idx] = C[idx] + v;
                }
            }
    }
}

// ---------------------------------------------------------------------------
extern "C" void kernel_launch(void* const* d_in, const int* in_sizes, int n_in,
                              void* d_out, int out_size, void* d_ws, size_t ws_size,
                              hipStream_t stream) {
    const float* x      = (const float*)d_in[0];
    const float* gamma1 = (const float*)d_in[1];
    const float* beta1  = (const float*)d_in[2];
    const float* Wq     = (const float*)d_in[3];
    const float* Wk     = (const float*)d_in[4];
    const float* Wv     = (const float*)d_in[5];
    const float* Wo     = (const float*)d_in[6];
    const float* bo     = (const float*)d_in[7];
    const float* gamma2 = (const float*)d_in[8];
    const float* beta2  = (const float*)d_in[9];
    const float* W1     = (const float*)d_in[10];
    const float* b1     = (const float*)d_in[11];
    const float* W2     = (const float*)d_in[12];
    const float* b2     = (const float*)d_in[13];
    float* out = (float*)d_out;

    char* ws = (char*)d_ws;
    const size_t SZ = (size_t)M_ * E_ * 2;     // 67,108,864 B
    // slot lifetimes:
    //  slot0: hbf (LN1->QKV)        then vt   (transpose->PV)
    //  slot1: qbf (QKV->QK^T)       then h2   (LN2->FF)
    //  slot2: kbf (QKV->QK^T)       then ffb lower half (FF)
    //  slot3: vtmp (QKV->transpose) then attn (PV->proj), then ffb upper half
    //  slot4: Sp (QK^T->PV)
    bf16* hbf  = (bf16*)(ws + 0 * SZ);
    bf16* vt   = (bf16*)(ws + 0 * SZ);
    bf16* qbf  = (bf16*)(ws + 1 * SZ);
    bf16* kbf  = (bf16*)(ws + 2 * SZ);
    bf16* vtmp = (bf16*)(ws + 3 * SZ);
    bf16* Sp   = (bf16*)(ws + 4 * SZ);
    bf16* attn = vtmp;
    bf16* h2   = qbf;
    bf16* ffb  = kbf;                          // spans slots 2+3
    size_t woff = 5 * SZ;
    bf16* Wqb = (bf16*)(ws + woff); woff += (size_t)E_ * E_ * 2;
    bf16* Wkb = (bf16*)(ws + woff); woff += (size_t)E_ * E_ * 2;
    bf16* Wvb = (bf16*)(ws + woff); woff += (size_t)E_ * E_ * 2;
    bf16* Wob = (bf16*)(ws + woff); woff += (size_t)E_ * E_ * 2;
    bf16* W1b = (bf16*)(ws + woff); woff += (size_t)FF_ * E_ * 2;
    bf16* W2b = (bf16*)(ws + woff); woff += (size_t)FF_ * E_ * 2;

    cvt_kernel<<<2048, 256, 0, stream>>>(Wq, Wqb, E_ * E_ / 8);
    cvt_kernel<<<2048, 256, 0, stream>>>(Wk, Wkb, E_ * E_ / 8);
    cvt_kernel<<<2048, 256, 0, stream>>>(Wv, Wvb, E_ * E_ / 8);
    cvt_kernel<<<2048, 256, 0, stream>>>(Wo, Wob, E_ * E_ / 8);
    cvt_kernel<<<8192, 256, 0, stream>>>(W1, W1b, FF_ * E_ / 8);
    cvt_kernel<<<8192, 256, 0, stream>>>(W2, W2b, FF_ * E_ / 8);

    ln_kernel<<<M_, 256, 0, stream>>>(x, gamma1, beta1, hbf);

    dim3 blk512(512);
    // fused QKV: one [6144, E] weight matrix; outputs q|k|vtmp (contiguous slots)
    dim3 gQKV(M_ / 256, 3 * E_ / 256, 1);   // (64, 24)
    gemm256<7><<<gQKV, blk512, 0, stream>>>(hbf, Wqb, E_, E_, E_, E_, 0, 0, 0,
                                            qbf, nullptr, nullptr, 1.f, 0);
    // v transpose: vtmp [b][t][h] -> vt [b][h][t]
    dim3 gT(T_ / 64, E_ / 64, B_);          // (32, 32, 8)
    transpose_kernel<<<gT, 256, 0, stream>>>(vtmp, vt);

    // QK^T (causal-skip), scaled
    dim3 gAttn(T_ / 256, T_ / 256, B_);     // (8, 8, 8)
    gemm256<1><<<gAttn, blk512, 0, stream>>>(qbf, kbf, E_, E_, E_, T_,
                                             (long)T_ * E_, (long)T_ * E_, (long)T_ * T_,
                                             Sp, nullptr, nullptr, 0.022097086912079612f, 0);
    softmax_kernel<<<M_, 256, 0, stream>>>(Sp);
    // P @ V  (vt is [B, HS, T], K-contiguous)
    gemm256<3><<<gAttn, blk512, 0, stream>>>(Sp, vt, T_, T_, T_, E_,
                                             (long)T_ * T_, (long)E_ * T_, (long)T_ * E_,
                                             attn, nullptr, nullptr, 1.f, 0);
    // out-projection + residual -> d_out (fp32)
    dim3 gProj(M_ / 256, E_ / 256, 1);      // (64, 8)
    gemm256<4><<<gProj, blk512, 0, stream>>>(attn, Wob, E_, E_, E_, E_, 0, 0, 0,
                                             out, bo, x, 1.f, 0);
    ln_kernel<<<M_, 256, 0, stream>>>(out, gamma2, beta2, h2);
    // FF in two 4096-wide slices
    dim3 gFF1(M_ / 256, 4096 / 256, 1);     // (64, 16)
    dim3 gFF2(M_ / 256, E_ / 256, 1);       // (64, 8)
    for (int s5 = 0; s5 < 2; s5++) {
        gemm256<5><<<gFF1, blk512, 0, stream>>>(h2, W1b + (size_t)s5 * 4096 * E_,
                                                E_, E_, E_, 4096, 0, 0, 0,
                                                ffb, b1 + s5 * 4096, nullptr, 1.f, 0);
        gemm256<6><<<gFF2, blk512, 0, stream>>>(ffb, W2b + s5 * 4096,
                                                4096, 4096, FF_, E_, 0, 0, 0,
                                                out, b2, nullptr, 1.f, s5 == 0 ? 1 : 0);
    }
}